// Round 1
// baseline (942.061 us; speedup 1.0000x reference)
//
#include <hip/hip_runtime.h>
#include <cmath>

// ---------------- prep: degree count, scan -> CSR, boundaries ----------------

__global__ __launch_bounds__(256) void count_k(const int* __restrict__ dst, int* __restrict__ cnt, int E) {
  int e = blockIdx.x * 256 + threadIdx.x;
  if (e < E) atomicAdd(&cnt[dst[e]], 1);
}

__global__ __launch_bounds__(256) void scanA(const int* __restrict__ cnt, int* __restrict__ part, int n) {
  int b = blockIdx.x, t = threadIdx.x;
  int base = b * 1024 + t * 4;
  int sum = 0;
  #pragma unroll
  for (int j = 0; j < 4; ++j) { int i = base + j; if (i < n) sum += cnt[i]; }
  __shared__ int ls[256];
  ls[t] = sum; __syncthreads();
  for (int off = 128; off > 0; off >>= 1) { if (t < off) ls[t] += ls[t + off]; __syncthreads(); }
  if (t == 0) part[b] = ls[0];
}

__global__ __launch_bounds__(128) void scanB(int* __restrict__ part, int nb,
                                             int* __restrict__ row_start, int n, int eTot) {
  __shared__ int ls[128];
  int t = threadIdx.x;
  int v = (t < nb) ? part[t] : 0;
  ls[t] = v; __syncthreads();
  for (int off = 1; off < 128; off <<= 1) {
    int x = (t >= off) ? ls[t - off] : 0;
    __syncthreads();
    ls[t] += x;
    __syncthreads();
  }
  if (t < nb) part[t] = (t == 0) ? 0 : ls[t - 1];
  if (t == 0) row_start[n] = eTot;
}

__global__ __launch_bounds__(256) void scanC(const int* __restrict__ cnt, const int* __restrict__ part,
                                             int* __restrict__ row_start, int* __restrict__ cursor,
                                             float* __restrict__ dis, int n) {
  int b = blockIdx.x, t = threadIdx.x;
  int base = b * 1024 + t * 4;
  int v[4]; int sum = 0;
  #pragma unroll
  for (int j = 0; j < 4; ++j) { int i = base + j; v[j] = (i < n) ? cnt[i] : 0; sum += v[j]; }
  __shared__ int ls[256];
  ls[t] = sum; __syncthreads();
  for (int off = 1; off < 256; off <<= 1) {
    int x = (t >= off) ? ls[t - off] : 0;
    __syncthreads();
    ls[t] += x;
    __syncthreads();
  }
  int run = part[b] + ((t == 0) ? 0 : ls[t - 1]);
  #pragma unroll
  for (int j = 0; j < 4; ++j) {
    int i = base + j;
    if (i < n) { row_start[i] = run; cursor[i] = run; dis[i] = rsqrtf((float)v[j] + 1.0f); }
    run += v[j];
  }
}

__global__ __launch_bounds__(256) void fill_k(const int* __restrict__ src, const int* __restrict__ dst,
                                              int* __restrict__ cursor, int* __restrict__ csr_src,
                                              float* __restrict__ csr_ds, const float* __restrict__ dis, int E) {
  int e = blockIdx.x * 256 + threadIdx.x;
  if (e < E) {
    int d = dst[e]; int s = src[e];
    int pos = atomicAdd(&cursor[d], 1);
    csr_src[pos] = s;
    csr_ds[pos] = dis[s];
  }
}

// graph segment boundaries (batch is sorted); gstart has G+1 entries
__global__ __launch_bounds__(256) void bounds_k(const int* __restrict__ batch, int* __restrict__ gstart,
                                                int n, int G) {
  int i = blockIdx.x * 256 + threadIdx.x;
  if (i >= n) return;
  int b = batch[i];
  int prev = (i == 0) ? -1 : batch[i - 1];
  for (int g = prev + 1; g <= b; ++g) gstart[g] = i;
  if (i == n - 1) { for (int g = b + 1; g <= G; ++g) gstart[g] = n; }
}

// ---------------- per-layer kernels ----------------

// Y[N,64] = X[N,64] @ W[64,64]. One wave per block, one row per lane, W rows via scalar loads.
__global__ __launch_bounds__(64) void gemm64(const float* __restrict__ X, const float* __restrict__ W,
                                             float* __restrict__ Y, int n) {
  __shared__ float Xs[64][65];  // +1 pad: bank = (lane+k)%32 -> 2-way (free)
  int r0 = blockIdx.x * 64;
  int lane = threadIdx.x;
  for (int rr = 0; rr < 64; ++rr) {
    int r = r0 + rr;
    Xs[rr][lane] = (r < n) ? X[(size_t)r * 64 + lane] : 0.f;
  }
  __syncthreads();
  float acc[64];
  #pragma unroll
  for (int c = 0; c < 64; ++c) acc[c] = 0.f;
  #pragma unroll 2
  for (int k = 0; k < 64; ++k) {
    float xv = Xs[lane][k];
    const float* wr = W + k * 64;   // wave-uniform -> s_load
    #pragma unroll
    for (int c = 0; c < 64; ++c) acc[c] += xv * wr[c];
  }
  int r = r0 + lane;
  if (r < n) {
    float4* y4 = (float4*)(Y + (size_t)r * 64);
    #pragma unroll
    for (int c = 0; c < 16; ++c)
      y4[c] = make_float4(acc[4*c], acc[4*c+1], acc[4*c+2], acc[4*c+3]);
  }
}

// Hout[n][f] = relu( sum_e dis[src]*dis[n]*Hlin[src][f] + dis[n]^2*Hlin[n][f] + b[f] )
// one wave per node, lane = feature
__global__ __launch_bounds__(256) void agg_k(const float* __restrict__ Hlin, const int* __restrict__ csr_src,
                                             const float* __restrict__ csr_ds, const int* __restrict__ row_start,
                                             const float* __restrict__ dis, const float* __restrict__ bias,
                                             float* __restrict__ Hout, int n) {
  int node = blockIdx.x * 4 + (threadIdx.x >> 6);
  int lane = threadIdx.x & 63;
  if (node >= n) return;
  float dn = dis[node];
  float acc = Hlin[(size_t)node * 64 + lane] * dn * dn;
  int e0 = row_start[node], e1 = row_start[node + 1];
  for (int e = e0; e < e1; ++e) {
    int s = csr_src[e];
    float w = csr_ds[e] * dn;
    acc += Hlin[(size_t)s * 64 + lane] * w;
  }
  float v = acc + bias[lane];
  Hout[(size_t)node * 64 + lane] = v > 0.f ? v : 0.f;
}

// one block (4 waves) per graph; z[g][0:64]+=mean, [64:128]+=max, [128:192]+=sum
__global__ __launch_bounds__(256) void pool_k(const float* __restrict__ H, const int* __restrict__ gstart,
                                              float* __restrict__ z) {
  int g = blockIdx.x;
  int lane = threadIdx.x & 63;
  int w = threadIdx.x >> 6;
  int i0 = gstart[g], i1 = gstart[g + 1];
  float s = 0.f, m = 0.f;  // m init 0 == max(segment_max, 0) in reference (h >= 0)
  for (int i = i0 + w; i < i1; i += 4) {
    float v = H[(size_t)i * 64 + lane];
    s += v; m = fmaxf(m, v);
  }
  __shared__ float ss[4][64], sm[4][64];
  ss[w][lane] = s; sm[w][lane] = m;
  __syncthreads();
  if (w == 0) {
    s = ss[0][lane] + ss[1][lane] + ss[2][lane] + ss[3][lane];
    m = fmaxf(fmaxf(sm[0][lane], sm[1][lane]), fmaxf(sm[2][lane], sm[3][lane]));
    float cntf = (float)(i1 - i0);
    float mean = (cntf > 0.f) ? s / cntf : 0.f;
    z[g * 192 + lane]       += mean;
    z[g * 192 + 64 + lane]  += m;
    z[g * 192 + 128 + lane] += s;
  }
}

// ---------------- MLP head + log_softmax ----------------
__global__ __launch_bounds__(64) void mlp_k(const float* __restrict__ z,
                                            const float* __restrict__ fc1w, const float* __restrict__ fc1b,
                                            const float* __restrict__ fc2w, const float* __restrict__ fc2b,
                                            const float* __restrict__ fc3w, const float* __restrict__ fc3b,
                                            float* __restrict__ out) {
  int g = blockIdx.x; int t = threadIdx.x;
  __shared__ float zr[192], a1[64], a2[32], a3[10];
  for (int i = t; i < 192; i += 64) zr[i] = z[g * 192 + i];
  __syncthreads();
  float acc = fc1b[t];
  for (int k = 0; k < 192; ++k) acc += zr[k] * fc1w[k * 64 + t];
  a1[t] = fmaxf(acc, 0.f);
  __syncthreads();
  if (t < 32) {
    float a = fc2b[t];
    #pragma unroll
    for (int k = 0; k < 64; ++k) a += a1[k] * fc2w[k * 32 + t];
    a2[t] = fmaxf(a, 0.f);
  }
  __syncthreads();
  if (t < 10) {
    float a = fc3b[t];
    #pragma unroll
    for (int k = 0; k < 32; ++k) a += a2[k] * fc3w[k * 10 + t];
    a3[t] = a;
  }
  __syncthreads();
  if (t == 0) {
    float mx = a3[0];
    for (int i = 1; i < 10; ++i) mx = fmaxf(mx, a3[i]);
    float sum = 0.f;
    for (int i = 0; i < 10; ++i) sum += expf(a3[i] - mx);
    float lse = mx + logf(sum);
    for (int i = 0; i < 10; ++i) out[g * 10 + i] = a3[i] - lse;
  }
}

extern "C" void kernel_launch(void* const* d_in, const int* in_sizes, int n_in,
                              void* d_out, int out_size, void* d_ws, size_t ws_size,
                              hipStream_t stream) {
  const float* x    = (const float*)d_in[0];
  const int*   ei   = (const int*)  d_in[1];
  const int*   batch= (const int*)  d_in[2];
  const float* W1   = (const float*)d_in[3];
  const float* b1   = (const float*)d_in[4];
  const float* W2   = (const float*)d_in[5];
  const float* b2   = (const float*)d_in[6];
  const float* W3   = (const float*)d_in[7];
  const float* b3   = (const float*)d_in[8];
  const float* fc1w = (const float*)d_in[9];
  const float* fc1b = (const float*)d_in[10];
  const float* fc2w = (const float*)d_in[11];
  const float* fc2b = (const float*)d_in[12];
  const float* fc3w = (const float*)d_in[13];
  const float* fc3b = (const float*)d_in[14];
  float* out = (float*)d_out;

  const int N = in_sizes[0] / 64;
  const int E = in_sizes[1] / 2;
  const int G = out_size / 10;
  const int* src = ei;
  const int* dst = ei + E;

  char* p = (char*)d_ws;
  auto alloc = [&](size_t bytes) -> void* {
    void* r = (void*)p; p += (bytes + 255) & ~(size_t)255; return r;
  };
  int*   cnt       = (int*)  alloc((size_t)N * 4);
  int*   part      = (int*)  alloc(128 * 4);
  int*   row_start = (int*)  alloc((size_t)(N + 1) * 4);
  int*   cursor    = (int*)  alloc((size_t)N * 4);
  float* dis       = (float*)alloc((size_t)N * 4);
  int*   gstart    = (int*)  alloc((size_t)(G + 1) * 4);
  int*   csr_src   = (int*)  alloc((size_t)E * 4);
  float* csr_ds    = (float*)alloc((size_t)E * 4);
  float* hlin      = (float*)alloc((size_t)N * 64 * 4);
  float* hA        = (float*)alloc((size_t)N * 64 * 4);
  float* zbuf      = (float*)alloc((size_t)G * 192 * 4);
  (void)ws_size; (void)n_in;

  hipMemsetAsync(cnt, 0, (size_t)N * 4, stream);
  hipMemsetAsync(zbuf, 0, (size_t)G * 192 * 4, stream);

  int ebl = (E + 255) / 256;
  int nb  = (N + 1023) / 1024;
  count_k<<<ebl, 256, 0, stream>>>(dst, cnt, E);
  scanA<<<nb, 256, 0, stream>>>(cnt, part, N);
  scanB<<<1, 128, 0, stream>>>(part, nb, row_start, N, E);
  scanC<<<nb, 256, 0, stream>>>(cnt, part, row_start, cursor, dis, N);
  fill_k<<<ebl, 256, 0, stream>>>(src, dst, cursor, csr_src, csr_ds, dis, E);
  bounds_k<<<(N + 255) / 256, 256, 0, stream>>>(batch, gstart, N, G);

  int gb = (N + 63) / 64;
  int ab = (N + 3) / 4;
  // layer 1
  gemm64<<<gb, 64, 0, stream>>>(x, W1, hlin, N);
  agg_k<<<ab, 256, 0, stream>>>(hlin, csr_src, csr_ds, row_start, dis, b1, hA, N);
  pool_k<<<G, 256, 0, stream>>>(hA, gstart, zbuf);
  // layer 2
  gemm64<<<gb, 64, 0, stream>>>(hA, W2, hlin, N);
  agg_k<<<ab, 256, 0, stream>>>(hlin, csr_src, csr_ds, row_start, dis, b2, hA, N);
  pool_k<<<G, 256, 0, stream>>>(hA, gstart, zbuf);
  // layer 3
  gemm64<<<gb, 64, 0, stream>>>(hA, W3, hlin, N);
  agg_k<<<ab, 256, 0, stream>>>(hlin, csr_src, csr_ds, row_start, dis, b3, hA, N);
  pool_k<<<G, 256, 0, stream>>>(hA, gstart, zbuf);

  mlp_k<<<G, 64, 0, stream>>>(zbuf, fc1w, fc1b, fc2w, fc2b, fc3w, fc3b, out);
}

// Round 2
// 639.868 us; speedup vs baseline: 1.4723x; 1.4723x over previous
//
#include <hip/hip_runtime.h>
#include <cmath>

typedef unsigned int uint;

// ---- bf16 helpers (manual, RNE) ----
__device__ inline float bflo(uint u) { return __uint_as_float(u << 16); }
__device__ inline float bfhi(uint u) { return __uint_as_float(u & 0xffff0000u); }
__device__ inline uint bfpack(float a, float b) {
  uint ua = __float_as_uint(a), ub = __float_as_uint(b);
  uint ra = (ua + 0x7fffu + ((ua >> 16) & 1u)) >> 16;
  uint rb = (ub + 0x7fffu + ((ub >> 16) & 1u)) >> 16;
  return ra | (rb << 16);
}

// ---------------- prep: degree count, scan -> CSR, boundaries ----------------

__global__ __launch_bounds__(256) void count_k(const int* __restrict__ dst, int* __restrict__ cnt, int E) {
  int e = blockIdx.x * 256 + threadIdx.x;
  if (e < E) atomicAdd(&cnt[dst[e]], 1);
}

__global__ __launch_bounds__(256) void scanA(const int* __restrict__ cnt, int* __restrict__ part, int n) {
  int b = blockIdx.x, t = threadIdx.x;
  int base = b * 1024 + t * 4;
  int sum = 0;
  #pragma unroll
  for (int j = 0; j < 4; ++j) { int i = base + j; if (i < n) sum += cnt[i]; }
  __shared__ int ls[256];
  ls[t] = sum; __syncthreads();
  for (int off = 128; off > 0; off >>= 1) { if (t < off) ls[t] += ls[t + off]; __syncthreads(); }
  if (t == 0) part[b] = ls[0];
}

__global__ __launch_bounds__(128) void scanB(int* __restrict__ part, int nb,
                                             int* __restrict__ row_start, int n, int eTot) {
  __shared__ int ls[128];
  int t = threadIdx.x;
  int v = (t < nb) ? part[t] : 0;
  ls[t] = v; __syncthreads();
  for (int off = 1; off < 128; off <<= 1) {
    int x = (t >= off) ? ls[t - off] : 0;
    __syncthreads();
    ls[t] += x;
    __syncthreads();
  }
  if (t < nb) part[t] = (t == 0) ? 0 : ls[t - 1];
  if (t == 0) row_start[n] = eTot;
}

__global__ __launch_bounds__(256) void scanC(const int* __restrict__ cnt, const int* __restrict__ part,
                                             int* __restrict__ row_start, int* __restrict__ cursor,
                                             float* __restrict__ dis, int n) {
  int b = blockIdx.x, t = threadIdx.x;
  int base = b * 1024 + t * 4;
  int v[4]; int sum = 0;
  #pragma unroll
  for (int j = 0; j < 4; ++j) { int i = base + j; v[j] = (i < n) ? cnt[i] : 0; sum += v[j]; }
  __shared__ int ls[256];
  ls[t] = sum; __syncthreads();
  for (int off = 1; off < 256; off <<= 1) {
    int x = (t >= off) ? ls[t - off] : 0;
    __syncthreads();
    ls[t] += x;
    __syncthreads();
  }
  int run = part[b] + ((t == 0) ? 0 : ls[t - 1]);
  #pragma unroll
  for (int j = 0; j < 4; ++j) {
    int i = base + j;
    if (i < n) { row_start[i] = run; cursor[i] = run; dis[i] = rsqrtf((float)v[j] + 1.0f); }
    run += v[j];
  }
}

// packed CSR entry: (src, dis[src] bits) -> one 8B store per edge
__global__ __launch_bounds__(256) void fill_k(const int* __restrict__ src, const int* __restrict__ dst,
                                              int* __restrict__ cursor, int2* __restrict__ csr,
                                              const float* __restrict__ dis, int E) {
  int e = blockIdx.x * 256 + threadIdx.x;
  if (e < E) {
    int d = dst[e]; int s = src[e];
    int pos = atomicAdd(&cursor[d], 1);
    csr[pos] = make_int2(s, __float_as_int(dis[s]));
  }
}

__global__ __launch_bounds__(256) void bounds_k(const int* __restrict__ batch, int* __restrict__ gstart,
                                                int n, int G) {
  int i = blockIdx.x * 256 + threadIdx.x;
  if (i >= n) return;
  int b = batch[i];
  int prev = (i == 0) ? -1 : batch[i - 1];
  for (int g = prev + 1; g <= b; ++g) gstart[g] = i;
  if (i == n - 1) { for (int g = b + 1; g <= G; ++g) gstart[g] = n; }
}

// ---------------- GEMM: Y[N,64](bf16) = X[N,64] @ W[64,64] ----------------
// 256 threads = 4 waves; block covers 64 rows; wave w computes cols [16w,16w+16).
// LDS tile XOR-swizzled: logical (r,c) at Xs[r][(c+r)&63] -> 2-way banks (free).

__global__ __launch_bounds__(256) void gemm_f32_k(const float* __restrict__ X, const float* __restrict__ W,
                                                  ushort* __restrict__ Y, int n) {
  __shared__ float Xs[64][64];
  int r0 = blockIdx.x * 64;
  int t = threadIdx.x;
  #pragma unroll
  for (int i = 0; i < 4; ++i) {
    int idx = t + i * 256;          // 0..1023 = 64 rows x 16 float4
    int rr = idx >> 4;
    int c4 = (idx & 15) * 4;
    int r = r0 + rr;
    float4 v = (r < n) ? ((const float4*)(X + (size_t)r * 64))[idx & 15] : make_float4(0, 0, 0, 0);
    Xs[rr][(c4 + 0 + rr) & 63] = v.x;
    Xs[rr][(c4 + 1 + rr) & 63] = v.y;
    Xs[rr][(c4 + 2 + rr) & 63] = v.z;
    Xs[rr][(c4 + 3 + rr) & 63] = v.w;
  }
  __syncthreads();
  int lane = t & 63;
  int w = t >> 6;
  float acc[16];
  #pragma unroll
  for (int c = 0; c < 16; ++c) acc[c] = 0.f;
  #pragma unroll 4
  for (int k = 0; k < 64; ++k) {
    float xv = Xs[lane][(k + lane) & 63];
    const float* wr = W + k * 64 + w * 16;   // wave-uniform -> s_load
    #pragma unroll
    for (int c = 0; c < 16; ++c) acc[c] += xv * wr[c];
  }
  int r = r0 + lane;
  if (r < n) {
    uint4* yr = (uint4*)(Y + (size_t)r * 64 + w * 16);
    yr[0] = make_uint4(bfpack(acc[0], acc[1]), bfpack(acc[2], acc[3]),
                       bfpack(acc[4], acc[5]), bfpack(acc[6], acc[7]));
    yr[1] = make_uint4(bfpack(acc[8], acc[9]), bfpack(acc[10], acc[11]),
                       bfpack(acc[12], acc[13]), bfpack(acc[14], acc[15]));
  }
}

__global__ __launch_bounds__(256) void gemm_bf16_k(const ushort* __restrict__ X, const float* __restrict__ W,
                                                   ushort* __restrict__ Y, int n) {
  __shared__ float Xs[64][64];
  int r0 = blockIdx.x * 64;
  int t = threadIdx.x;
  #pragma unroll
  for (int i = 0; i < 4; ++i) {
    int idx = t + i * 256;          // 64 rows x 16 quads of bf16
    int rr = idx >> 4;
    int c4 = (idx & 15) * 4;
    int r = r0 + rr;
    uint2 v = (r < n) ? ((const uint2*)(X + (size_t)r * 64))[idx & 15] : make_uint2(0, 0);
    Xs[rr][(c4 + 0 + rr) & 63] = bflo(v.x);
    Xs[rr][(c4 + 1 + rr) & 63] = bfhi(v.x);
    Xs[rr][(c4 + 2 + rr) & 63] = bflo(v.y);
    Xs[rr][(c4 + 3 + rr) & 63] = bfhi(v.y);
  }
  __syncthreads();
  int lane = t & 63;
  int w = t >> 6;
  float acc[16];
  #pragma unroll
  for (int c = 0; c < 16; ++c) acc[c] = 0.f;
  #pragma unroll 4
  for (int k = 0; k < 64; ++k) {
    float xv = Xs[lane][(k + lane) & 63];
    const float* wr = W + k * 64 + w * 16;
    #pragma unroll
    for (int c = 0; c < 16; ++c) acc[c] += xv * wr[c];
  }
  int r = r0 + lane;
  if (r < n) {
    uint4* yr = (uint4*)(Y + (size_t)r * 64 + w * 16);
    yr[0] = make_uint4(bfpack(acc[0], acc[1]), bfpack(acc[2], acc[3]),
                       bfpack(acc[4], acc[5]), bfpack(acc[6], acc[7]));
    yr[1] = make_uint4(bfpack(acc[8], acc[9]), bfpack(acc[10], acc[11]),
                       bfpack(acc[12], acc[13]), bfpack(acc[14], acc[15]));
  }
}

// ---------------- aggregation: one wave per node, 8 edges in flight ----------------
// lane = 8*slot + fl : slot picks edge, fl picks feature octet (8 bf16 = 16B load).

__global__ __launch_bounds__(256) void agg_k(const ushort* __restrict__ Hlin,
                                             const int2* __restrict__ csr,
                                             const int* __restrict__ row_start,
                                             const float* __restrict__ dis,
                                             const float* __restrict__ bias,
                                             ushort* __restrict__ Hout, int n) {
  int node = blockIdx.x * 4 + (threadIdx.x >> 6);
  if (node >= n) return;
  int lane = threadIdx.x & 63;
  int slot = lane >> 3;
  int fl = lane & 7;
  float dn = dis[node];
  float acc[8];
  #pragma unroll
  for (int j = 0; j < 8; ++j) acc[j] = 0.f;
  if (slot == 0) {  // self-loop term, counted once
    uint4 v = ((const uint4*)(Hlin + (size_t)node * 64))[fl];
    float s = dn * dn;
    acc[0] = bflo(v.x) * s; acc[1] = bfhi(v.x) * s;
    acc[2] = bflo(v.y) * s; acc[3] = bfhi(v.y) * s;
    acc[4] = bflo(v.z) * s; acc[5] = bfhi(v.z) * s;
    acc[6] = bflo(v.w) * s; acc[7] = bfhi(v.w) * s;
  }
  int e0 = row_start[node], e1 = row_start[node + 1];
  for (int e = e0 + slot; e < e1; e += 8) {
    int2 sd = csr[e];
    float w = __int_as_float(sd.y) * dn;
    uint4 v = ((const uint4*)(Hlin + (size_t)sd.x * 64))[fl];
    acc[0] += bflo(v.x) * w; acc[1] += bfhi(v.x) * w;
    acc[2] += bflo(v.y) * w; acc[3] += bfhi(v.y) * w;
    acc[4] += bflo(v.z) * w; acc[5] += bfhi(v.z) * w;
    acc[6] += bflo(v.w) * w; acc[7] += bfhi(v.w) * w;
  }
  #pragma unroll
  for (int m = 8; m <= 32; m <<= 1) {
    #pragma unroll
    for (int j = 0; j < 8; ++j) acc[j] += __shfl_xor(acc[j], m, 64);
  }
  if (slot == 0) {
    const float4* b4 = (const float4*)(bias + fl * 8);
    float4 ba = b4[0], bb = b4[1];
    float r0 = fmaxf(acc[0] + ba.x, 0.f), r1 = fmaxf(acc[1] + ba.y, 0.f);
    float r2 = fmaxf(acc[2] + ba.z, 0.f), r3 = fmaxf(acc[3] + ba.w, 0.f);
    float r4 = fmaxf(acc[4] + bb.x, 0.f), r5 = fmaxf(acc[5] + bb.y, 0.f);
    float r6 = fmaxf(acc[6] + bb.z, 0.f), r7 = fmaxf(acc[7] + bb.w, 0.f);
    ((uint4*)(Hout + (size_t)node * 64))[fl] =
        make_uint4(bfpack(r0, r1), bfpack(r2, r3), bfpack(r4, r5), bfpack(r6, r7));
  }
}

// ---------------- pooling: one block per graph, 32 rows in flight ----------------

__global__ __launch_bounds__(256) void pool_k(const ushort* __restrict__ H, const int* __restrict__ gstart,
                                              float* __restrict__ z) {
  int g = blockIdx.x;
  int t = threadIdx.x;
  int lane = t & 63, w = t >> 6;
  int slot = lane >> 3, fl = lane & 7;
  int i0 = gstart[g], i1 = gstart[g + 1];
  float s[8], m[8];
  #pragma unroll
  for (int j = 0; j < 8; ++j) { s[j] = 0.f; m[j] = 0.f; }  // max clamped at 0 (h>=0)
  for (int i = i0 + w * 8 + slot; i < i1; i += 32) {
    uint4 v = ((const uint4*)(H + (size_t)i * 64))[fl];
    float f[8] = { bflo(v.x), bfhi(v.x), bflo(v.y), bfhi(v.y),
                   bflo(v.z), bfhi(v.z), bflo(v.w), bfhi(v.w) };
    #pragma unroll
    for (int j = 0; j < 8; ++j) { s[j] += f[j]; m[j] = fmaxf(m[j], f[j]); }
  }
  #pragma unroll
  for (int msk = 8; msk <= 32; msk <<= 1) {
    #pragma unroll
    for (int j = 0; j < 8; ++j) {
      s[j] += __shfl_xor(s[j], msk, 64);
      m[j] = fmaxf(m[j], __shfl_xor(m[j], msk, 64));
    }
  }
  __shared__ float ss[4][64], sm[4][64];
  if (slot == 0) {
    #pragma unroll
    for (int j = 0; j < 8; ++j) { ss[w][fl * 8 + j] = s[j]; sm[w][fl * 8 + j] = m[j]; }
  }
  __syncthreads();
  if (t < 64) {
    float S = ss[0][t] + ss[1][t] + ss[2][t] + ss[3][t];
    float M = fmaxf(fmaxf(sm[0][t], sm[1][t]), fmaxf(sm[2][t], sm[3][t]));
    float cnt = (float)(i1 - i0);
    float mean = (cnt > 0.f) ? S / cnt : 0.f;
    z[g * 192 + t]       += mean;
    z[g * 192 + 64 + t]  += M;
    z[g * 192 + 128 + t] += S;
  }
}

// ---------------- MLP head + log_softmax ----------------
__global__ __launch_bounds__(64) void mlp_k(const float* __restrict__ z,
                                            const float* __restrict__ fc1w, const float* __restrict__ fc1b,
                                            const float* __restrict__ fc2w, const float* __restrict__ fc2b,
                                            const float* __restrict__ fc3w, const float* __restrict__ fc3b,
                                            float* __restrict__ out) {
  int g = blockIdx.x; int t = threadIdx.x;
  __shared__ float zr[192], a1[64], a2[32], a3[10];
  for (int i = t; i < 192; i += 64) zr[i] = z[g * 192 + i];
  __syncthreads();
  float acc = fc1b[t];
  for (int k = 0; k < 192; ++k) acc += zr[k] * fc1w[k * 64 + t];
  a1[t] = fmaxf(acc, 0.f);
  __syncthreads();
  if (t < 32) {
    float a = fc2b[t];
    #pragma unroll
    for (int k = 0; k < 64; ++k) a += a1[k] * fc2w[k * 32 + t];
    a2[t] = fmaxf(a, 0.f);
  }
  __syncthreads();
  if (t < 10) {
    float a = fc3b[t];
    #pragma unroll
    for (int k = 0; k < 32; ++k) a += a2[k] * fc3w[k * 10 + t];
    a3[t] = a;
  }
  __syncthreads();
  if (t == 0) {
    float mx = a3[0];
    for (int i = 1; i < 10; ++i) mx = fmaxf(mx, a3[i]);
    float sum = 0.f;
    for (int i = 0; i < 10; ++i) sum += expf(a3[i] - mx);
    float lse = mx + logf(sum);
    for (int i = 0; i < 10; ++i) out[g * 10 + i] = a3[i] - lse;
  }
}

extern "C" void kernel_launch(void* const* d_in, const int* in_sizes, int n_in,
                              void* d_out, int out_size, void* d_ws, size_t ws_size,
                              hipStream_t stream) {
  const float* x    = (const float*)d_in[0];
  const int*   ei   = (const int*)  d_in[1];
  const int*   batch= (const int*)  d_in[2];
  const float* W1   = (const float*)d_in[3];
  const float* b1   = (const float*)d_in[4];
  const float* W2   = (const float*)d_in[5];
  const float* b2   = (const float*)d_in[6];
  const float* W3   = (const float*)d_in[7];
  const float* b3   = (const float*)d_in[8];
  const float* fc1w = (const float*)d_in[9];
  const float* fc1b = (const float*)d_in[10];
  const float* fc2w = (const float*)d_in[11];
  const float* fc2b = (const float*)d_in[12];
  const float* fc3w = (const float*)d_in[13];
  const float* fc3b = (const float*)d_in[14];
  float* out = (float*)d_out;

  const int N = in_sizes[0] / 64;
  const int E = in_sizes[1] / 2;
  const int G = out_size / 10;
  const int* src = ei;
  const int* dst = ei + E;

  char* p = (char*)d_ws;
  auto alloc = [&](size_t bytes) -> void* {
    void* r = (void*)p; p += (bytes + 255) & ~(size_t)255; return r;
  };
  int*    cnt       = (int*)   alloc((size_t)N * 4);
  int*    part      = (int*)   alloc(128 * 4);
  int*    row_start = (int*)   alloc((size_t)(N + 1) * 4);
  int*    cursor    = (int*)   alloc((size_t)N * 4);
  float*  dis       = (float*) alloc((size_t)N * 4);
  int*    gstart    = (int*)   alloc((size_t)(G + 1) * 4);
  int2*   csr       = (int2*)  alloc((size_t)E * 8);
  ushort* hlin      = (ushort*)alloc((size_t)N * 64 * 2);
  ushort* hA        = (ushort*)alloc((size_t)N * 64 * 2);
  float*  zbuf      = (float*) alloc((size_t)G * 192 * 4);
  (void)ws_size; (void)n_in;

  hipMemsetAsync(cnt, 0, (size_t)N * 4, stream);
  hipMemsetAsync(zbuf, 0, (size_t)G * 192 * 4, stream);

  int ebl = (E + 255) / 256;
  int nb  = (N + 1023) / 1024;
  count_k<<<ebl, 256, 0, stream>>>(dst, cnt, E);
  scanA<<<nb, 256, 0, stream>>>(cnt, part, N);
  scanB<<<1, 128, 0, stream>>>(part, nb, row_start, N, E);
  scanC<<<nb, 256, 0, stream>>>(cnt, part, row_start, cursor, dis, N);
  fill_k<<<ebl, 256, 0, stream>>>(src, dst, cursor, csr, dis, E);
  bounds_k<<<(N + 255) / 256, 256, 0, stream>>>(batch, gstart, N, G);

  int gb = (N + 63) / 64;
  int ab = (N + 3) / 4;
  // layer 1
  gemm_f32_k<<<gb, 256, 0, stream>>>(x, W1, hlin, N);
  agg_k<<<ab, 256, 0, stream>>>(hlin, csr, row_start, dis, b1, hA, N);
  pool_k<<<G, 256, 0, stream>>>(hA, gstart, zbuf);
  // layer 2
  gemm_bf16_k<<<gb, 256, 0, stream>>>(hA, W2, hlin, N);
  agg_k<<<ab, 256, 0, stream>>>(hlin, csr, row_start, dis, b2, hA, N);
  pool_k<<<G, 256, 0, stream>>>(hA, gstart, zbuf);
  // layer 3
  gemm_bf16_k<<<gb, 256, 0, stream>>>(hA, W3, hlin, N);
  agg_k<<<ab, 256, 0, stream>>>(hlin, csr, row_start, dis, b3, hA, N);
  pool_k<<<G, 256, 0, stream>>>(hA, gstart, zbuf);

  mlp_k<<<G, 64, 0, stream>>>(zbuf, fc1w, fc1b, fc2w, fc2b, fc3w, fc3b, out);
}